// Round 9
// baseline (168.740 us; speedup 1.0000x reference)
//
#include <hip/hip_runtime.h>
#include <cstdint>

#define B_ROWS 32768
#define DIM    256
#define KCODES 1024
#define NSPLIT 2

typedef _Float16 f16x8 __attribute__((ext_vector_type(8)));
typedef float    f32x4 __attribute__((ext_vector_type(4)));

// ws layout:
//   [0, 512K)        cb_hi  (fp16, per-code 512B rows, 16B-granule XOR-swizzled)
//   [512K, 1M)       cb_lo  (fp16, scaled x2048, same swizzle)
//   [1M, 1M+4K)      inv_norm (float[1024])
//   [1M+4K, +512K)   cand   (float2[NSPLIT][B_ROWS] = {dot, bitcast(k)})

// ---------------- prep: codebook -> fp16 hi/lo (swizzled) + 1/norm ----------------
__global__ __launch_bounds__(64) void vq_prep(const float* __restrict__ cb,
                                              _Float16* __restrict__ hi,
                                              _Float16* __restrict__ lo,
                                              float* __restrict__ inv_norm) {
  const int k = blockIdx.x;
  const int lane = threadIdx.x;
  float4 c = reinterpret_cast<const float4*>(cb)[k * 64 + lane];
  float nrm = c.x * c.x + c.y * c.y + c.z * c.z + c.w * c.w;
#pragma unroll
  for (int off = 32; off; off >>= 1) nrm += __shfl_xor(nrm, off);
  if (lane == 0) inv_norm[k] = 1.0f / nrm;

  float f[4] = {c.x, c.y, c.z, c.w};
  _Float16 h[4], l[4];
#pragma unroll
  for (int i = 0; i < 4; ++i) {
    h[i] = (_Float16)f[i];
    l[i] = (_Float16)((f[i] - (float)h[i]) * 2048.0f);
  }
  // granule swizzle: phys = g ^ (code & 15) within the code's 512B row
  const int phys = (lane >> 1) ^ (k & 15);
  const int byteoff = k * 512 + phys * 16 + (lane & 1) * 8;
  *reinterpret_cast<uint2*>((char*)hi + byteoff) = *reinterpret_cast<uint2*>(h);
  *reinterpret_cast<uint2*>((char*)lo + byteoff) = *reinterpret_cast<uint2*>(l);
}

__device__ __forceinline__ void gld16(const void* g, void* l) {
  __builtin_amdgcn_global_load_lds(
      (const __attribute__((address_space(1))) uint32_t*)g,
      (__attribute__((address_space(3))) uint32_t*)l, 16, 0, 0);
}

#define MFMA16(a, b, acc) __builtin_amdgcn_mfma_f32_16x16x32_f16((a), (b), (acc), 0, 0, 0)

// ---------------- main: split-fp16 MFMA GEMM + per-split argmax (deferred epilogue) ----------------
// R11 = R6 (best main, 58us: 2-phase schedule, 4-deep LDS, counted vmcnt, XCD pairing)
// + DEFERRED epilogue: the ~65-op argmax update for tile t runs during tile t+1's
// ds-read shadow (half in ph0, half in ph1, placed after the ds_read issue and before
// the s_barrier). Previously all 8 waves ran it in lockstep between ph1's MFMA drain
// and the loop-top barrier (exposed VALU), then ph0's lgkmcnt(0) exposed ds latency.
// Now the VALU covers the ds latency. +24 VGPR prev-acc state (LDS-capped at 2
// blocks/CU so register headroom is free). Numerics identical.
__global__ __launch_bounds__(256, 2) void vq_main(const float* __restrict__ emb,
                                                  const _Float16* __restrict__ cbh,
                                                  const _Float16* __restrict__ cbl,
                                                  const float* __restrict__ inv_g,
                                                  float2* __restrict__ cand) {
  __shared__ uint4 Btile[4][1024];   // 4 x 16KB: per tile [0,8K) hi, [8K,16K) lo
  __shared__ float inv_s[KCODES];

  const int flat = threadIdx.x;
  const int wave = flat >> 6;
  const int lane = flat & 63;
  const int quad = lane >> 4;
  const int lr   = lane & 15;

  // same-XCD pairing: blocks b and b+8 are the two splits of one rowblk
  const int b = blockIdx.x;
  const int rowblk = ((b >> 4) << 3) | (b & 7);
  const int split  = (b >> 3) & 1;
  const int t0 = split * 32;         // 32 t-iters of 16 codes each = 512 codes
  const int tend = t0 + 32;

  reinterpret_cast<float4*>(inv_s)[flat] = reinterpret_cast<const float4*>(inv_g)[flat];

  // A fragments: 32 rows/wave (2 subtiles of 16), whole K-depth, hi+lo, in registers.
  f16x8 Ah[2][8], Al[2][8];
  const int row0 = rowblk * 128 + wave * 32;
#pragma unroll
  for (int s = 0; s < 2; ++s) {
    const float* rp = emb + (size_t)(row0 + s * 16 + lr) * DIM;
#pragma unroll
    for (int c = 0; c < 8; ++c) {
      const float* p = rp + c * 32 + quad * 8;
      float4 f0 = *reinterpret_cast<const float4*>(p);
      float4 f1 = *reinterpret_cast<const float4*>(p + 4);
      float f[8] = {f0.x, f0.y, f0.z, f0.w, f1.x, f1.y, f1.z, f1.w};
      f16x8 h, l;
#pragma unroll
      for (int j = 0; j < 8; ++j) {
        _Float16 hv = (_Float16)f[j];
        h[j] = hv;
        l[j] = (_Float16)((f[j] - (float)hv) * 2048.0f);
      }
      Ah[s][c] = h;
      Al[s][c] = l;
    }
  }

  // inv_s ds_write visible to all waves BEFORE any async stage is issued.
  __syncthreads();

  auto stage = [&](int t) {
    const char* srcH = (const char*)cbh + t * 8192;
    const char* srcL = (const char*)cbl + t * 8192;
    char* dst = (char*)&Btile[t & 3][0];
    const int off = flat * 16;
    gld16(srcH + off,        dst + off);
    gld16(srcH + 4096 + off, dst + 4096 + off);
    gld16(srcL + off,        dst + 8192 + off);
    gld16(srcL + 4096 + off, dst + 12288 + off);
  };
  stage(t0);
  stage(t0 + 1);
  stage(t0 + 2);

  float bg[2][4], bd[2][4];
  int   bk[2][4];
#pragma unroll
  for (int s = 0; s < 2; ++s)
#pragma unroll
    for (int r = 0; r < 4; ++r) { bg[s][r] = -1.0f; bd[s][r] = 0.0f; bk[s][r] = t0 * 16; }

  // deferred-epilogue state (prev iteration's accumulators)
  f32x4 pA0 = {0,0,0,0}, pA1 = {0,0,0,0};
  f32x4 pBa0 = {0,0,0,0}, pBa1 = {0,0,0,0};
  f32x4 pBb0 = {0,0,0,0}, pBb1 = {0,0,0,0};
  float pinl = 0.0f;
  int   pn = t0 * 16;

  for (int t = t0; t < tend; ++t) {
    // counted wait: own stage(t) loads (oldest 4) complete; up to 2 newer tiles
    // (8 loads) stay in flight across the barrier. Tail peels 8 -> 4 -> 0.
    const int rem = tend - t;
    if (rem >= 3)      asm volatile("s_waitcnt vmcnt(8)" ::: "memory");
    else if (rem == 2) asm volatile("s_waitcnt vmcnt(4)" ::: "memory");
    else               asm volatile("s_waitcnt vmcnt(0)" ::: "memory");
    __builtin_amdgcn_sched_barrier(0);
    __builtin_amdgcn_s_barrier();          // tile t fully in LDS (all waves vmcnt-waited)
    __builtin_amdgcn_sched_barrier(0);

    const char* buf = (const char*)&Btile[t & 3][0];

    f32x4 aA0  = {0, 0, 0, 0}, aA1  = {0, 0, 0, 0};
    f32x4 aBa0 = {0, 0, 0, 0}, aBa1 = {0, 0, 0, 0};   // Al * Bh
    f32x4 aBb0 = {0, 0, 0, 0}, aBb1 = {0, 0, 0, 0};   // Ah * Bl

    // ---------------- phase 0: c = 0..3 ----------------
    {
      f16x8 bh[4], bl[4];
#pragma unroll
      for (int c = 0; c < 4; ++c) {
        const int g = (((c * 4 + quad) ^ lr) * 16) + lr * 512;  // de-swizzled granule
        bh[c] = *reinterpret_cast<const f16x8*>(buf + g);
        bl[c] = *reinterpret_cast<const f16x8*>(buf + 8192 + g);
      }
      if (rem > 3) stage(t + 3);           // prefetch issue overlaps this phase's reads

      // deferred epilogue, half A (prev tile, subtile 0) — runs in the ds-read shadow
      if (t != t0) {
#pragma unroll
        for (int r = 0; r < 4; ++r) {
          float d0 = pA0[r] + (pBa0[r] + pBb0[r]) * 4.8828125e-4f;   // 1/2048
          float g0 = d0 * d0 * pinl;
          if (g0 > bg[0][r]) { bg[0][r] = g0; bd[0][r] = d0; bk[0][r] = pn; }
        }
      }
      __builtin_amdgcn_sched_barrier(0);
      __builtin_amdgcn_s_barrier();
      asm volatile("s_waitcnt lgkmcnt(0)" ::: "memory");
      __builtin_amdgcn_sched_barrier(0);
      __builtin_amdgcn_s_setprio(1);
#pragma unroll
      for (int c = 0; c < 4; ++c) {
        aA0  = MFMA16(Ah[0][c], bh[c], aA0);
        aA1  = MFMA16(Ah[1][c], bh[c], aA1);
        aBa0 = MFMA16(Al[0][c], bh[c], aBa0);
        aBa1 = MFMA16(Al[1][c], bh[c], aBa1);
        aBb0 = MFMA16(Ah[0][c], bl[c], aBb0);
        aBb1 = MFMA16(Ah[1][c], bl[c], aBb1);
      }
      __builtin_amdgcn_s_setprio(0);
      __builtin_amdgcn_sched_barrier(0);
    }

    // ---------------- phase 1: c = 4..7 ----------------
    {
      f16x8 bh[4], bl[4];
#pragma unroll
      for (int c = 0; c < 4; ++c) {
        const int g = ((((c + 4) * 4 + quad) ^ lr) * 16) + lr * 512;
        bh[c] = *reinterpret_cast<const f16x8*>(buf + g);
        bl[c] = *reinterpret_cast<const f16x8*>(buf + 8192 + g);
      }

      // deferred epilogue, half B (prev tile, subtile 1)
      if (t != t0) {
#pragma unroll
        for (int r = 0; r < 4; ++r) {
          float d1 = pA1[r] + (pBa1[r] + pBb1[r]) * 4.8828125e-4f;
          float g1 = d1 * d1 * pinl;
          if (g1 > bg[1][r]) { bg[1][r] = g1; bd[1][r] = d1; bk[1][r] = pn; }
        }
      }
      __builtin_amdgcn_sched_barrier(0);
      __builtin_amdgcn_s_barrier();
      asm volatile("s_waitcnt lgkmcnt(0)" ::: "memory");
      __builtin_amdgcn_sched_barrier(0);
      __builtin_amdgcn_s_setprio(1);
#pragma unroll
      for (int c = 0; c < 4; ++c) {
        aA0  = MFMA16(Ah[0][c + 4], bh[c], aA0);
        aA1  = MFMA16(Ah[1][c + 4], bh[c], aA1);
        aBa0 = MFMA16(Al[0][c + 4], bh[c], aBa0);
        aBa1 = MFMA16(Al[1][c + 4], bh[c], aBa1);
        aBb0 = MFMA16(Ah[0][c + 4], bl[c], aBb0);
        aBb1 = MFMA16(Ah[1][c + 4], bl[c], aBb1);
      }
      __builtin_amdgcn_s_setprio(0);
      __builtin_amdgcn_sched_barrier(0);
    }

    // save current accs as prev; preload prev inl (LDS read consumed next iter)
    pA0 = aA0; pA1 = aA1; pBa0 = aBa0; pBa1 = aBa1; pBb0 = aBb0; pBb1 = aBb1;
    pn = t * 16 + lr;
    pinl = inv_s[pn];
  }

  // final epilogue for the last tile
#pragma unroll
  for (int r = 0; r < 4; ++r) {
    float d0 = pA0[r] + (pBa0[r] + pBb0[r]) * 4.8828125e-4f;
    float g0 = d0 * d0 * pinl;
    if (g0 > bg[0][r]) { bg[0][r] = g0; bd[0][r] = d0; bk[0][r] = pn; }
    float d1 = pA1[r] + (pBa1[r] + pBb1[r]) * 4.8828125e-4f;
    float g1 = d1 * d1 * pinl;
    if (g1 > bg[1][r]) { bg[1][r] = g1; bd[1][r] = d1; bk[1][r] = pn; }
  }

  // cross-lane argmax over the 16 cols of each quad (rows = quad*4+reg per C layout)
#pragma unroll
  for (int s = 0; s < 2; ++s) {
#pragma unroll
    for (int r = 0; r < 4; ++r) {
      float g = bg[s][r]; int k = bk[s][r]; float d = bd[s][r];
#pragma unroll
      for (int m = 1; m < 16; m <<= 1) {
        float g2 = __shfl_xor(g, m);
        int   k2 = __shfl_xor(k, m);
        float d2 = __shfl_xor(d, m);
        if (g2 > g || (g2 == g && k2 < k)) { g = g2; k = k2; d = d2; }
      }
      if (lr == 0) {
        const int row = row0 + s * 16 + quad * 4 + r;
        cand[(size_t)split * B_ROWS + row] = make_float2(d, __int_as_float(k));
      }
    }
  }
}

// ---------------- reduce: pick best split candidate, write z + index ----------------
// 2048 blocks x 16 rows (4 waves x 4 rows unrolled) + nontemporal z stores.
__global__ __launch_bounds__(256) void vq_reduce(const float2* __restrict__ cand,
                                                 const float* __restrict__ inv_g,
                                                 const float* __restrict__ cb,
                                                 float* __restrict__ out) {
  const int wave = threadIdx.x >> 6;
  const int lane = threadIdx.x & 63;
  const int base = blockIdx.x * 16;

#pragma unroll
  for (int i = 0; i < 4; ++i) {
    const int row = base + i * 4 + wave;
    float2 ca = cand[row];
    float2 cbv = cand[(size_t)B_ROWS + row];
    int k0 = __float_as_int(ca.y);
    int k1 = __float_as_int(cbv.y);
    float ga = ca.x * ca.x * inv_g[k0];
    float gb = cbv.x * cbv.x * inv_g[k1];
    float d_; int k_;
    if (ga > gb || (ga == gb && k0 < k1)) { d_ = ca.x; k_ = k0; }
    else                                  { d_ = cbv.x; k_ = k1; }
    const float alpha = d_ * inv_g[k_];
    float4 c4 = reinterpret_cast<const float4*>(cb)[k_ * 64 + lane];
    f32x4 z = {alpha * c4.x, alpha * c4.y, alpha * c4.z, alpha * c4.w};
    __builtin_nontemporal_store(z, reinterpret_cast<f32x4*>(out) + (size_t)row * 64 + lane);
    if (lane == 0) out[(size_t)B_ROWS * DIM + row] = (float)k_;
  }
}

extern "C" void kernel_launch(void* const* d_in, const int* in_sizes, int n_in,
                              void* d_out, int out_size, void* d_ws, size_t ws_size,
                              hipStream_t stream) {
  const float* emb = (const float*)d_in[0];
  const float* cb  = (const float*)d_in[1];
  _Float16* cbh = (_Float16*)d_ws;
  _Float16* cbl = (_Float16*)((char*)d_ws + (512 << 10));
  float*    inv = (float*)((char*)d_ws + (1 << 20));
  float2*   cand = (float2*)((char*)d_ws + (1 << 20) + 4096);

  vq_prep<<<KCODES, 64, 0, stream>>>(cb, cbh, cbl, inv);
  vq_main<<<(B_ROWS / 128) * NSPLIT, 256, 0, stream>>>(emb, cbh, cbl, inv, cand);
  vq_reduce<<<B_ROWS / 16, 256, 0, stream>>>(cand, inv, cb, (float*)d_out);
}

// Round 10
// 132.714 us; speedup vs baseline: 1.2715x; 1.2715x over previous
//
#include <hip/hip_runtime.h>
#include <cstdint>

#define B_ROWS 32768
#define DIM    256
#define KCODES 1024
#define NSPLIT 2

typedef _Float16 f16x8 __attribute__((ext_vector_type(8)));
typedef float    f32x4 __attribute__((ext_vector_type(4)));

// ws layout:
//   [0, 512K)        cb_hi  (fp16, per-code 512B rows, 16B-granule XOR-swizzled)
//   [512K, 1M)       cb_lo  (fp16, scaled x2048, same swizzle)
//   [1M, 1M+4K)      inv_norm (float[1024])
//   [1M+4K, +512K)   cand   (float2[NSPLIT][B_ROWS] = {dot, bitcast(k)})

// ---------------- prep: codebook -> fp16 hi/lo (swizzled) + 1/norm ----------------
__global__ __launch_bounds__(64) void vq_prep(const float* __restrict__ cb,
                                              _Float16* __restrict__ hi,
                                              _Float16* __restrict__ lo,
                                              float* __restrict__ inv_norm) {
  const int k = blockIdx.x;
  const int lane = threadIdx.x;
  float4 c = reinterpret_cast<const float4*>(cb)[k * 64 + lane];
  float nrm = c.x * c.x + c.y * c.y + c.z * c.z + c.w * c.w;
#pragma unroll
  for (int off = 32; off; off >>= 1) nrm += __shfl_xor(nrm, off);
  if (lane == 0) inv_norm[k] = 1.0f / nrm;

  float f[4] = {c.x, c.y, c.z, c.w};
  _Float16 h[4], l[4];
#pragma unroll
  for (int i = 0; i < 4; ++i) {
    h[i] = (_Float16)f[i];
    l[i] = (_Float16)((f[i] - (float)h[i]) * 2048.0f);
  }
  // granule swizzle: phys = g ^ (code & 15) within the code's 512B row
  const int phys = (lane >> 1) ^ (k & 15);
  const int byteoff = k * 512 + phys * 16 + (lane & 1) * 8;
  *reinterpret_cast<uint2*>((char*)hi + byteoff) = *reinterpret_cast<uint2*>(h);
  *reinterpret_cast<uint2*>((char*)lo + byteoff) = *reinterpret_cast<uint2*>(l);
}

__device__ __forceinline__ void gld16(const void* g, void* l) {
  __builtin_amdgcn_global_load_lds(
      (const __attribute__((address_space(1))) uint32_t*)g,
      (__attribute__((address_space(3))) uint32_t*)l, 16, 0, 0);
}

#define MFMA16(a, b, acc) __builtin_amdgcn_mfma_f32_16x16x32_f16((a), (b), (acc), 0, 0, 0)

// ---------------- main: split-fp16 MFMA GEMM + per-split argmax candidates ----------------
// R12 main = R6 byte-for-byte (session-best 57.7-59.8us; 116 VGPR, no spill):
// 2-phase m201-style schedule, 4-deep LDS buffers, counted vmcnt (never 0 in steady
// state), XCD-pair swizzle, split accumulator chains. R11's deferred epilogue REVERTED
// (it pushed past the compiler's 128-VGPR budget -> 18MB/dispatch scratch spill).
__global__ __launch_bounds__(256, 2) void vq_main(const float* __restrict__ emb,
                                                  const _Float16* __restrict__ cbh,
                                                  const _Float16* __restrict__ cbl,
                                                  const float* __restrict__ inv_g,
                                                  float2* __restrict__ cand) {
  __shared__ uint4 Btile[4][1024];   // 4 x 16KB: per tile [0,8K) hi, [8K,16K) lo
  __shared__ float inv_s[KCODES];

  const int flat = threadIdx.x;
  const int wave = flat >> 6;
  const int lane = flat & 63;
  const int quad = lane >> 4;
  const int lr   = lane & 15;

  // same-XCD pairing: blocks b and b+8 are the two splits of one rowblk
  const int b = blockIdx.x;
  const int rowblk = ((b >> 4) << 3) | (b & 7);
  const int split  = (b >> 3) & 1;
  const int t0 = split * 32;         // 32 t-iters of 16 codes each = 512 codes
  const int tend = t0 + 32;

  reinterpret_cast<float4*>(inv_s)[flat] = reinterpret_cast<const float4*>(inv_g)[flat];

  // A fragments: 32 rows/wave (2 subtiles of 16), whole K-depth, hi+lo, in registers.
  f16x8 Ah[2][8], Al[2][8];
  const int row0 = rowblk * 128 + wave * 32;
#pragma unroll
  for (int s = 0; s < 2; ++s) {
    const float* rp = emb + (size_t)(row0 + s * 16 + lr) * DIM;
#pragma unroll
    for (int c = 0; c < 8; ++c) {
      const float* p = rp + c * 32 + quad * 8;
      float4 f0 = *reinterpret_cast<const float4*>(p);
      float4 f1 = *reinterpret_cast<const float4*>(p + 4);
      float f[8] = {f0.x, f0.y, f0.z, f0.w, f1.x, f1.y, f1.z, f1.w};
      f16x8 h, l;
#pragma unroll
      for (int j = 0; j < 8; ++j) {
        _Float16 hv = (_Float16)f[j];
        h[j] = hv;
        l[j] = (_Float16)((f[j] - (float)hv) * 2048.0f);
      }
      Ah[s][c] = h;
      Al[s][c] = l;
    }
  }

  // inv_s ds_write visible to all waves BEFORE any async stage is issued.
  __syncthreads();

  auto stage = [&](int t) {
    const char* srcH = (const char*)cbh + t * 8192;
    const char* srcL = (const char*)cbl + t * 8192;
    char* dst = (char*)&Btile[t & 3][0];
    const int off = flat * 16;
    gld16(srcH + off,        dst + off);
    gld16(srcH + 4096 + off, dst + 4096 + off);
    gld16(srcL + off,        dst + 8192 + off);
    gld16(srcL + 4096 + off, dst + 12288 + off);
  };
  stage(t0);
  stage(t0 + 1);
  stage(t0 + 2);

  float bg[2][4], bd[2][4];
  int   bk[2][4];
#pragma unroll
  for (int s = 0; s < 2; ++s)
#pragma unroll
    for (int r = 0; r < 4; ++r) { bg[s][r] = -1.0f; bd[s][r] = 0.0f; bk[s][r] = t0 * 16; }

  for (int t = t0; t < tend; ++t) {
    // counted wait: own stage(t) loads (oldest 4) complete; up to 2 newer tiles
    // (8 loads) stay in flight across the barrier. Tail peels 8 -> 4 -> 0.
    const int rem = tend - t;
    if (rem >= 3)      asm volatile("s_waitcnt vmcnt(8)" ::: "memory");
    else if (rem == 2) asm volatile("s_waitcnt vmcnt(4)" ::: "memory");
    else               asm volatile("s_waitcnt vmcnt(0)" ::: "memory");
    __builtin_amdgcn_sched_barrier(0);
    __builtin_amdgcn_s_barrier();          // tile t fully in LDS (all waves vmcnt-waited)
    __builtin_amdgcn_sched_barrier(0);

    const char* buf = (const char*)&Btile[t & 3][0];

    f32x4 aA0  = {0, 0, 0, 0}, aA1  = {0, 0, 0, 0};
    f32x4 aBa0 = {0, 0, 0, 0}, aBa1 = {0, 0, 0, 0};   // Al * Bh
    f32x4 aBb0 = {0, 0, 0, 0}, aBb1 = {0, 0, 0, 0};   // Ah * Bl

    // ---------------- phase 0: c = 0..3 ----------------
    {
      f16x8 bh[4], bl[4];
#pragma unroll
      for (int c = 0; c < 4; ++c) {
        const int g = (((c * 4 + quad) ^ lr) * 16) + lr * 512;  // de-swizzled granule
        bh[c] = *reinterpret_cast<const f16x8*>(buf + g);
        bl[c] = *reinterpret_cast<const f16x8*>(buf + 8192 + g);
      }
      if (rem > 3) stage(t + 3);           // prefetch issue overlaps this phase's reads
      __builtin_amdgcn_sched_barrier(0);
      __builtin_amdgcn_s_barrier();
      asm volatile("s_waitcnt lgkmcnt(0)" ::: "memory");
      __builtin_amdgcn_sched_barrier(0);
      __builtin_amdgcn_s_setprio(1);
#pragma unroll
      for (int c = 0; c < 4; ++c) {
        aA0  = MFMA16(Ah[0][c], bh[c], aA0);
        aA1  = MFMA16(Ah[1][c], bh[c], aA1);
        aBa0 = MFMA16(Al[0][c], bh[c], aBa0);
        aBa1 = MFMA16(Al[1][c], bh[c], aBa1);
        aBb0 = MFMA16(Ah[0][c], bl[c], aBb0);
        aBb1 = MFMA16(Ah[1][c], bl[c], aBb1);
      }
      __builtin_amdgcn_s_setprio(0);
      __builtin_amdgcn_sched_barrier(0);
    }

    // ---------------- phase 1: c = 4..7 ----------------
    {
      f16x8 bh[4], bl[4];
#pragma unroll
      for (int c = 0; c < 4; ++c) {
        const int g = ((((c + 4) * 4 + quad) ^ lr) * 16) + lr * 512;
        bh[c] = *reinterpret_cast<const f16x8*>(buf + g);
        bl[c] = *reinterpret_cast<const f16x8*>(buf + 8192 + g);
      }
      __builtin_amdgcn_sched_barrier(0);
      __builtin_amdgcn_s_barrier();
      asm volatile("s_waitcnt lgkmcnt(0)" ::: "memory");
      __builtin_amdgcn_sched_barrier(0);
      __builtin_amdgcn_s_setprio(1);
#pragma unroll
      for (int c = 0; c < 4; ++c) {
        aA0  = MFMA16(Ah[0][c + 4], bh[c], aA0);
        aA1  = MFMA16(Ah[1][c + 4], bh[c], aA1);
        aBa0 = MFMA16(Al[0][c + 4], bh[c], aBa0);
        aBa1 = MFMA16(Al[1][c + 4], bh[c], aBa1);
        aBb0 = MFMA16(Ah[0][c + 4], bl[c], aBb0);
        aBb1 = MFMA16(Ah[1][c + 4], bl[c], aBb1);
      }
      __builtin_amdgcn_s_setprio(0);
      __builtin_amdgcn_sched_barrier(0);
    }

    // ---------------- epilogue: per-code argmax update ----------------
    const int n = t * 16 + lr;             // C/D layout: col = lane&15
    const float inl = inv_s[n];
#pragma unroll
    for (int r = 0; r < 4; ++r) {
      float d0 = aA0[r] + (aBa0[r] + aBb0[r]) * 4.8828125e-4f;   // 1/2048
      float g0 = d0 * d0 * inl;
      if (g0 > bg[0][r]) { bg[0][r] = g0; bd[0][r] = d0; bk[0][r] = n; }
      float d1 = aA1[r] + (aBa1[r] + aBb1[r]) * 4.8828125e-4f;
      float g1 = d1 * d1 * inl;
      if (g1 > bg[1][r]) { bg[1][r] = g1; bd[1][r] = d1; bk[1][r] = n; }
    }
  }

  // cross-lane argmax over the 16 cols of each quad (rows = quad*4+reg per C layout)
#pragma unroll
  for (int s = 0; s < 2; ++s) {
#pragma unroll
    for (int r = 0; r < 4; ++r) {
      float g = bg[s][r]; int k = bk[s][r]; float d = bd[s][r];
#pragma unroll
      for (int m = 1; m < 16; m <<= 1) {
        float g2 = __shfl_xor(g, m);
        int   k2 = __shfl_xor(k, m);
        float d2 = __shfl_xor(d, m);
        if (g2 > g || (g2 == g && k2 < k)) { g = g2; k = k2; d = d2; }
      }
      if (lr == 0) {
        const int row = row0 + s * 16 + quad * 4 + r;
        cand[(size_t)split * B_ROWS + row] = make_float2(d, __int_as_float(k));
      }
    }
  }
}

// ---------------- reduce: pick best split candidate, write z + index ----------------
// R10's proven reduce: 2048 blocks x 16 rows (4 waves x 4 rows) + nontemporal z stores.
__global__ __launch_bounds__(256) void vq_reduce(const float2* __restrict__ cand,
                                                 const float* __restrict__ inv_g,
                                                 const float* __restrict__ cb,
                                                 float* __restrict__ out) {
  const int wave = threadIdx.x >> 6;
  const int lane = threadIdx.x & 63;
  const int base = blockIdx.x * 16;

#pragma unroll
  for (int i = 0; i < 4; ++i) {
    const int row = base + i * 4 + wave;
    float2 ca = cand[row];
    float2 cbv = cand[(size_t)B_ROWS + row];
    int k0 = __float_as_int(ca.y);
    int k1 = __float_as_int(cbv.y);
    float ga = ca.x * ca.x * inv_g[k0];
    float gb = cbv.x * cbv.x * inv_g[k1];
    float d_; int k_;
    if (ga > gb || (ga == gb && k0 < k1)) { d_ = ca.x; k_ = k0; }
    else                                  { d_ = cbv.x; k_ = k1; }
    const float alpha = d_ * inv_g[k_];
    float4 c4 = reinterpret_cast<const float4*>(cb)[k_ * 64 + lane];
    f32x4 z = {alpha * c4.x, alpha * c4.y, alpha * c4.z, alpha * c4.w};
    __builtin_nontemporal_store(z, reinterpret_cast<f32x4*>(out) + (size_t)row * 64 + lane);
    if (lane == 0) out[(size_t)B_ROWS * DIM + row] = (float)k_;
  }
}

extern "C" void kernel_launch(void* const* d_in, const int* in_sizes, int n_in,
                              void* d_out, int out_size, void* d_ws, size_t ws_size,
                              hipStream_t stream) {
  const float* emb = (const float*)d_in[0];
  const float* cb  = (const float*)d_in[1];
  _Float16* cbh = (_Float16*)d_ws;
  _Float16* cbl = (_Float16*)((char*)d_ws + (512 << 10));
  float*    inv = (float*)((char*)d_ws + (1 << 20));
  float2*   cand = (float2*)((char*)d_ws + (1 << 20) + 4096);

  vq_prep<<<KCODES, 64, 0, stream>>>(cb, cbh, cbl, inv);
  vq_main<<<(B_ROWS / 128) * NSPLIT, 256, 0, stream>>>(emb, cbh, cbl, inv, cand);
  vq_reduce<<<B_ROWS / 16, 256, 0, stream>>>(cand, inv, cb, (float*)d_out);
}